// Round 14
// baseline (328.083 us; speedup 1.0000x reference)
//
#include <hip/hip_runtime.h>
#include <math.h>

// L=1024 B=2 F=1024 E=2 H=2048 N=16 R=64 K=4, M=2048 rows (m = l*2+b).
// Round-14:
//   - gls2_k: 128x128 tile (m103 sweet spot), BK=64, wave=64x64 quadrant,
//     32 KB LDS union (doubles MFMA per staged byte vs 128x64). G1 + G5.
//     G5 split-K=4 (512 blocks).
//   - dispatch merges: memset(out) -> prep_k; memset(projb) -> conv2 prologue;
//     cvtp dt-half -> g4 A-staging (fp32->bf16 inline). 11 -> 9 dispatches.
//   - conv2 (tap-strip, r13 win), scan7 (native exp2), g3 unchanged.

typedef unsigned short u16;
typedef unsigned int u32;
typedef __attribute__((ext_vector_type(8))) short short8;
typedef __attribute__((ext_vector_type(4))) float floatx4;
typedef __attribute__((ext_vector_type(4))) u16 ushort4v;

__device__ __forceinline__ u16 f2bf(float f) {
    u32 u = __float_as_uint(f);
    return (u16)((u + 0x7fffu + ((u >> 16) & 1u)) >> 16);
}
__device__ __forceinline__ float bf2f(u16 v) {
    return __uint_as_float((u32)v << 16);
}
__device__ __forceinline__ float fexp2(float x) {
    return __builtin_amdgcn_exp2f(x);   // bare v_exp_f32
}

// 16-lane sum reduction on the VALU pipe (DPP), no DS ops.
__device__ __forceinline__ float dpp_red16(float v) {
    v += __uint_as_float((u32)__builtin_amdgcn_update_dpp(
        0, (int)__float_as_uint(v), 0xB1, 0xF, 0xF, true));
    v += __uint_as_float((u32)__builtin_amdgcn_update_dpp(
        0, (int)__float_as_uint(v), 0x4E, 0xF, 0xF, true));
    v += __uint_as_float((u32)__builtin_amdgcn_update_dpp(
        0, (int)__float_as_uint(v), 0x141, 0xF, 0xF, true));
    v += __uint_as_float((u32)__builtin_amdgcn_update_dpp(
        0, (int)__float_as_uint(v), 0x128, 0xF, 0xF, true));
    return v;
}

// async global->LDS, 16 bytes per lane
__device__ __forceinline__ void gl_lds16(const u16* g, u16* l) {
    auto gp = reinterpret_cast<const __attribute__((address_space(1))) u32*>(
        reinterpret_cast<uintptr_t>(g));
    auto lp = reinterpret_cast<__attribute__((address_space(3))) u32*>(
        reinterpret_cast<uintptr_t>(l));
    __builtin_amdgcn_global_load_lds(gp, lp, 16, 0, 0);
}

// ---------------- device transpose body (fp32 -> bf16, S[R][C] -> D[C][R]) --------
__device__ __forceinline__ void trans_dev(const float* __restrict__ S,
                                          u16* __restrict__ D, int R, int C,
                                          int bx, int by)
{
    __shared__ u16 t[64][65];
    int br = bx * 64;
    int bc = by * 64;
    int c = threadIdx.x & 63;
    int r0 = threadIdx.x >> 6;
#pragma unroll
    for (int i = 0; i < 16; ++i) {
        int r = r0 + i * 4;
        float v = 0.f;
        if (br + r < R && bc + c < C) v = S[(size_t)(br + r) * C + bc + c];
        t[r][c] = f2bf(v);
    }
    __syncthreads();
    int cc0 = threadIdx.x >> 4;
    int rr0 = (threadIdx.x & 15) * 4;
#pragma unroll
    for (int i = 0; i < 4; ++i) {
        int cc = i * 16 + cc0;
        if (bc + cc < C) {
            ushort4v o;
#pragma unroll
            for (int k = 0; k < 4; ++k) o[k] = t[rr0 + k][cc];
            *(ushort4v*)(D + (size_t)(bc + cc) * R + br + rr0) = o;
        }
    }
}

// ------ prep: all transposes + x convert + out zeroing, one launch (7776 blocks) ---
__global__ __launch_bounds__(256) void prep_k(
    const float* __restrict__ Wc, u16* __restrict__ WTc,
    const float* __restrict__ Wi, u16* __restrict__ WTi,
    const float* __restrict__ Wo, u16* __restrict__ WTo,
    const float* __restrict__ Ws, u16* __restrict__ WTs,
    const float* __restrict__ Wd, u16* __restrict__ WTd,
    const float* __restrict__ x,  u16* __restrict__ xb,
    float* __restrict__ outz)
{
    int b = blockIdx.x;
    if (b < 2048) { trans_dev(Wc, WTc, 4096, 2048, b & 63, b >> 6); return; }
    b -= 2048;
    if (b < 1024) { trans_dev(Wi, WTi, 1024, 4096, b & 15, b >> 4); return; }
    b -= 1024;
    if (b < 512)  { trans_dev(Wo, WTo, 2048, 1024, b & 31, b >> 5); return; }
    b -= 512;
    if (b < 64)   { trans_dev(Ws, WTs, 2048, 96,   b & 31, b >> 5); return; }
    b -= 64;
    if (b < 32)   { trans_dev(Wd, WTd, 64, 2048,   0,      b);      return; }
    b -= 32;
    if (b < 2048) {   // x fp32 -> bf16
        int i = (b * 256 + threadIdx.x) * 4;
        float4 v = *(const float4*)(x + i);
        u16 o[4] = {f2bf(v.x), f2bf(v.y), f2bf(v.z), f2bf(v.w)};
        *(ulong1*)(xb + i) = *(ulong1*)o;
        return;
    }
    b -= 2048;
    {   // zero out (split-K accumulation target), 2048 blocks x 1024 floats
        int i = (b * 256 + threadIdx.x) * 4;
        *(float4*)(outz + i) = make_float4(0.f, 0.f, 0.f, 0.f);
    }
}

// ---------------- bf16 [2048][2048] transpose (zT -> z_mh) ----------------
__global__ __launch_bounds__(256) void tbf_k(const u16* __restrict__ S,
                                             u16* __restrict__ D)
{
    __shared__ u16 t[64][68];
    int br = blockIdx.x * 64;
    int bc = blockIdx.y * 64;
    int c = threadIdx.x & 63;
    int r0 = threadIdx.x >> 6;
#pragma unroll
    for (int i = 0; i < 16; ++i) {
        int r = r0 + i * 4;
        t[r][c] = S[(size_t)(br + r) * 2048 + bc + c];
    }
    __syncthreads();
#pragma unroll
    for (int i = 0; i < 16; ++i) {
        int r = r0 + i * 4;
        D[(size_t)(bc + r) * 2048 + br + c] = t[c][r];
    }
}

// ------- cvtp: BC cols 0..31 of proj -> bc16 bf16 [2048][32] (64 blocks) ----------
__global__ __launch_bounds__(256) void cvtp_k(const float* __restrict__ proj,
                                              u16* __restrict__ bc)
{
    int g = blockIdx.x * 256 + threadIdx.x;
    int m = g >> 3, i = (g & 7) * 4;
    float4 v = *(const float4*)(proj + (size_t)m * 128 + i);
    u16 o[4] = {f2bf(v.x), f2bf(v.y), f2bf(v.z), f2bf(v.w)};
    *(ulong1*)(bc + (size_t)m * 32 + i) = *(ulong1*)o;
}

// ============ gls2: 128x128-tile GEMM, BK=64, wave = 64x64 quadrant ================
// MODE 0: G1 split — bn<2048: xs[m][h] via LDS repack; else resT[h][m] direct
// MODE 3: split-K (gridDim.z), fp32 atomicAdd into zeroed Cf
template<int MODE>
__global__ __launch_bounds__(256) void gls2_k(
    const u16* __restrict__ A, int lda,
    const u16* __restrict__ B, int ldb,
    float* __restrict__ Cf, int ldc,
    u16* __restrict__ Cb0, u16* __restrict__ Cb1, int nkt)
{
    __shared__ u16 S[128 * 128];          // As = S[0:8192], Bs = S[8192:16384]
    u16* As = S;
    u16* Bs = S + 8192;
    const int tid = threadIdx.x;
    const int bm = blockIdx.y * 128;
    const int bn = blockIdx.x * 128;
    const int kofs = (MODE == 3) ? blockIdx.z * nkt * 64 : 0;
    const int lane = tid & 63, wave = tid >> 6;
    const int wm = (wave & 1) * 64, wn = (wave >> 1) * 64;
    const int m16 = lane & 15, q = lane >> 4;
    floatx4 acc[4][4] = {};
    const int rsub = lane >> 3, pch = lane & 7;

    for (int kt = 0; kt < nkt; ++kt) {
        const int k0 = kofs + kt * 64;
#pragma unroll
        for (int i = 0; i < 4; ++i) {
            int r = i * 32 + wave * 8 + rsub;
            int c = pch ^ (r & 7);
            gl_lds16(A + (size_t)(bm + r) * lda + k0 + c * 8,
                     As + i * 2048 + wave * 512);
            gl_lds16(B + (size_t)(bn + r) * ldb + k0 + c * 8,
                     Bs + i * 2048 + wave * 512);
        }
        __syncthreads();

#pragma unroll
        for (int ks = 0; ks < 2; ++ks) {
            short8 af[4], bfr[4];
#pragma unroll
            for (int ti = 0; ti < 4; ++ti) {
                int r = wm + ti * 16 + m16;
                int p = (ks * 4 + q) ^ (r & 7);
                af[ti] = *(const short8*)(As + r * 64 + p * 8);
            }
#pragma unroll
            for (int tj = 0; tj < 4; ++tj) {
                int r = wn + tj * 16 + m16;
                int p = (ks * 4 + q) ^ (r & 7);
                bfr[tj] = *(const short8*)(Bs + r * 64 + p * 8);
            }
#pragma unroll
            for (int ti = 0; ti < 4; ++ti)
#pragma unroll
                for (int tj = 0; tj < 4; ++tj)
                    acc[ti][tj] = __builtin_amdgcn_mfma_f32_16x16x32_bf16(
                        af[ti], bfr[tj], acc[ti][tj], 0, 0, 0);
        }
        __syncthreads();
    }

    if (MODE == 3) {
#pragma unroll
        for (int tj = 0; tj < 4; ++tj) {
            int gn = bn + wn + tj * 16 + m16;
#pragma unroll
            for (int ti = 0; ti < 4; ++ti) {
                int gm0 = bm + wm + ti * 16 + q * 4;
#pragma unroll
                for (int r = 0; r < 4; ++r)
                    atomicAdd(Cf + (size_t)(gm0 + r) * ldc + gn, acc[ti][tj][r]);
            }
        }
        return;
    }
    if (bn >= 2048) {     // MODE 0 res-half -> resT [h][m], ushort4 along m
#pragma unroll
        for (int tj = 0; tj < 4; ++tj) {
            int gn = bn - 2048 + wn + tj * 16 + m16;
#pragma unroll
            for (int ti = 0; ti < 4; ++ti) {
                int gm0 = bm + wm + ti * 16 + q * 4;
                ushort4v h;
#pragma unroll
                for (int r = 0; r < 4; ++r) h[r] = f2bf(acc[ti][tj][r]);
                *(ushort4v*)(Cb1 + (size_t)gn * 2048 + gm0) = h;
            }
        }
        return;
    }
    // MODE 0 xs-half: repack [m][h] 128x128 tile via LDS (S reused, 32 KB)
#pragma unroll
    for (int tj = 0; tj < 4; ++tj) {
        int col = wn + tj * 16 + m16;
#pragma unroll
        for (int ti = 0; ti < 4; ++ti) {
            int lr0 = wm + ti * 16 + q * 4;
#pragma unroll
            for (int r = 0; r < 4; ++r)
                S[(lr0 + r) * 128 + col] = f2bf(acc[ti][tj][r]);
        }
    }
    __syncthreads();
    {
        int row = tid >> 1, half = tid & 1;
        u16* gdst = Cb0 + (size_t)(bm + row) * 2048 + bn + half * 64;
        const u16* lsrc = S + row * 128 + half * 64;
#pragma unroll
        for (int i = 0; i < 8; ++i)
            *(short8*)(gdst + i * 8) = *(const short8*)(lsrc + i * 8);
    }
}

// ================= conv2: tap-strip conv GEMM, tile 128x64 ========================
__global__ __launch_bounds__(256) void conv2_k(
    const u16* __restrict__ A,      // xsbf [2048][2048]
    const u16* __restrict__ B,      // WT_cv [2048][4096]
    const float* __restrict__ bias,
    u16* __restrict__ Cb0,          // u_mh [m][h]
    u16* __restrict__ Cb1,          // uT [h][m]
    float* __restrict__ projz)      // projb to zero (for g3)
{
    __shared__ u16 Astrip[136 * 64];
    __shared__ u16 Bs[4 * 64 * 64];
    const int tid = threadIdx.x;
    const int bm = blockIdx.y * 128;
    const int bn = blockIdx.x * 64;
    // zero projb slice (consumed by the NEXT kernel g3; ordering via dispatch)
    {
        int fb = blockIdx.y * gridDim.x + blockIdx.x;   // 0..511
        *(float2*)(projz + fb * 512 + tid * 2) = make_float2(0.f, 0.f);
    }
    const int gofs = (bn >= 1024) ? 1024 : 0;
    const int lane = tid & 63, wave = tid >> 6, wm = wave * 32;
    const int m16 = lane & 15, q = lane >> 4;
    floatx4 acc[2][4] = {};
    const int rsub = lane >> 3;
    const int pch  = lane & 7;

    for (int ch = 0; ch < 16; ++ch) {
        const int ck = ch * 64;
#pragma unroll
        for (int i = 0; i < 4; ++i) {
            int r = i * 32 + wave * 8 + rsub;
            int c = pch ^ (r & 7);
            int rg = bm + r - 6;
            if (rg < 0) rg = 0;
            gl_lds16(A + (size_t)rg * 2048 + gofs + ck + c * 8,
                     Astrip + i * 2048 + wave * 512);
        }
        if (wave == 0) {
            int r = 128 + rsub;
            int c = pch ^ (r & 7);
            int rg = bm + r - 6;
            if (rg > 2047) rg = 2047;
            gl_lds16(A + (size_t)rg * 2048 + gofs + ck + c * 8,
                     Astrip + 4 * 2048);
        }
#pragma unroll
        for (int t = 0; t < 4; ++t)
#pragma unroll
            for (int i = 0; i < 2; ++i) {
                int r = i * 32 + wave * 8 + rsub;
                int c = pch ^ (r & 7);
                gl_lds16(B + (size_t)(bn + r) * 4096 + t * 1024 + ck + c * 8,
                         Bs + t * 4096 + i * 2048 + wave * 512);
            }
        if (bm == 0) {
            asm volatile("s_waitcnt vmcnt(0)" ::: "memory");
            if (tid < 48)
                *(short8*)(Astrip + (tid >> 3) * 64 + (tid & 7) * 8) = short8{};
        }
        __syncthreads();

#pragma unroll
        for (int t = 0; t < 4; ++t) {
#pragma unroll
            for (int ks = 0; ks < 2; ++ks) {
                short8 af[2], bfr[4];
#pragma unroll
                for (int ti = 0; ti < 2; ++ti) {
                    int sr = wm + ti * 16 + m16 + 2 * t;
                    int p = (ks * 4 + q) ^ (sr & 7);
                    af[ti] = *(const short8*)(Astrip + sr * 64 + p * 8);
                }
#pragma unroll
                for (int tj = 0; tj < 4; ++tj) {
                    int br = tj * 16 + m16;
                    int p = (ks * 4 + q) ^ (br & 7);
                    bfr[tj] = *(const short8*)(Bs + t * 4096 + br * 64 + p * 8);
                }
#pragma unroll
                for (int ti = 0; ti < 2; ++ti)
#pragma unroll
                    for (int tj = 0; tj < 4; ++tj)
                        acc[ti][tj] = __builtin_amdgcn_mfma_f32_16x16x32_bf16(
                            af[ti], bfr[tj], acc[ti][tj], 0, 0, 0);
            }
        }
        __syncthreads();
    }

#pragma unroll
    for (int tj = 0; tj < 4; ++tj) {
        int gn = bn + tj * 16 + m16;
        float bv = bias[gn];
#pragma unroll
        for (int ti = 0; ti < 2; ++ti) {
            int lr0 = wm + ti * 16 + q * 4;
            ushort4v h;
#pragma unroll
            for (int r = 0; r < 4; ++r) {
                float v = acc[ti][tj][r] + bv;
                v = v / (1.f + __expf(-v));
                u16 hv = f2bf(v);
                h[r] = hv;
                Astrip[(lr0 + r) * 64 + tj * 16 + m16] = hv;
            }
            *(ushort4v*)(Cb1 + (size_t)gn * 2048 + bm + lr0) = h;
        }
    }
    __syncthreads();
    {
        int row = tid >> 1, half = tid & 1;
        u16* gdst = Cb0 + (size_t)(bm + row) * 2048 + bn + half * 32;
        const u16* lsrc = Astrip + row * 64 + half * 32;
#pragma unroll
        for (int i = 0; i < 4; ++i)
            *(short8*)(gdst + i * 8) = *(const short8*)(lsrc + i * 8);
    }
}

// ---------------- G3: proj = u @ W_ssm, split-K=8 MFMA, interleaved atomics --------
#define APAD 40
__global__ __launch_bounds__(256) void g3_k(
    const u16* __restrict__ A,
    const u16* __restrict__ Bw,
    float* __restrict__ proj)
{
    __shared__ u16 As[128 * APAD];
    __shared__ u16 Bs[64 * APAD];
    const int tid = threadIdx.x;
    const int bn = blockIdx.x * 64;
    const int bm = blockIdx.y * 128;
    const int kb = blockIdx.z * 256;
    const int lane = tid & 63, wave = tid >> 6, wm = wave * 32;
    const int m16 = lane & 15, q = lane >> 4;
    floatx4 acc[2][4] = {};
    const int ar = tid >> 2, ac = (tid & 3) * 8;

    for (int kt = 0; kt < 8; ++kt) {
        const int k0 = kb + kt * 32;
#pragma unroll
        for (int p = 0; p < 2; ++p) {
            int r = ar + p * 64;
            *(short8*)(As + r * APAD + ac) =
                *(const short8*)(A + (size_t)(bm + r) * 2048 + k0 + ac);
        }
        *(short8*)(Bs + ar * APAD + ac) =
            *(const short8*)(Bw + (size_t)(bn + ar) * 2048 + k0 + ac);
        __syncthreads();

        short8 af[2], bfr[4];
#pragma unroll
        for (int ti = 0; ti < 2; ++ti)
            af[ti] = *(const short8*)(As + (wm + ti * 16 + m16) * APAD + q * 8);
#pragma unroll
        for (int tj = 0; tj < 4; ++tj)
            bfr[tj] = *(const short8*)(Bs + (tj * 16 + m16) * APAD + q * 8);
#pragma unroll
        for (int ti = 0; ti < 2; ++ti)
#pragma unroll
            for (int tj = 0; tj < 4; ++tj)
                acc[ti][tj] = __builtin_amdgcn_mfma_f32_16x16x32_bf16(
                    af[ti], bfr[tj], acc[ti][tj], 0, 0, 0);
        __syncthreads();
    }

#pragma unroll
    for (int tj = 0; tj < 4; ++tj) {
        int gn = bn + tj * 16 + m16;
        if (gn >= 96) continue;
        int col = (gn < 16) ? (2 * gn) : (gn < 32 ? 2 * (gn - 16) + 1 : 32 + gn);
#pragma unroll
        for (int ti = 0; ti < 2; ++ti)
#pragma unroll
            for (int r = 0; r < 4; ++r) {
                int gm = bm + wm + ti * 16 + q * 4 + r;
                atomicAdd(proj + (size_t)gm * 128 + col, acc[ti][tj][r]);
            }
    }
}

// ------- G4: deltaT = clip(softplus(dtraw @ W_dt + b_dt))^T, dt converted inline ---
__global__ __launch_bounds__(256) void g4_k(
    const float* __restrict__ proj,   // [2048][128], dtraw at cols 64..127
    const u16* __restrict__ B,        // WT_dt bf16 [2048][64]
    const float* __restrict__ bias,
    float* __restrict__ Cf)           // deltaT fp32 [h][m]
{
    __shared__ u16 As[128 * APAD];
    __shared__ u16 Bs[64 * APAD];
    const int tid = threadIdx.x;
    const int bm = blockIdx.y * 128;
    const int bn = blockIdx.x * 64;
    const int lane = tid & 63, wave = tid >> 6, wm = wave * 32;
    const int m16 = lane & 15, q = lane >> 4;
    floatx4 acc[2][4] = {};
    const int ar = tid >> 2, ac = (tid & 3) * 8;

    for (int kt = 0; kt < 2; ++kt) {
        const int k0 = kt * 32;
#pragma unroll
        for (int p = 0; p < 2; ++p) {
            int r = ar + p * 64;
            const float* src = proj + (size_t)(bm + r) * 128 + 64 + k0 + ac;
            float4 v0 = *(const float4*)src;
            float4 v1 = *(const float4*)(src + 4);
            short8 v = {(short)f2bf(v0.x), (short)f2bf(v0.y), (short)f2bf(v0.z),
                        (short)f2bf(v0.w), (short)f2bf(v1.x), (short)f2bf(v1.y),
                        (short)f2bf(v1.z), (short)f2bf(v1.w)};
            *(short8*)(As + r * APAD + ac) = v;
        }
        *(short8*)(Bs + ar * APAD + ac) =
            *(const short8*)(B + (size_t)(bn + ar) * 64 + k0 + ac);
        __syncthreads();
        short8 af[2], bfr[4];
#pragma unroll
        for (int ti = 0; ti < 2; ++ti)
            af[ti] = *(const short8*)(As + (wm + ti * 16 + m16) * APAD + q * 8);
#pragma unroll
        for (int tj = 0; tj < 4; ++tj)
            bfr[tj] = *(const short8*)(Bs + (tj * 16 + m16) * APAD + q * 8);
#pragma unroll
        for (int ti = 0; ti < 2; ++ti)
#pragma unroll
            for (int tj = 0; tj < 4; ++tj)
                acc[ti][tj] = __builtin_amdgcn_mfma_f32_16x16x32_bf16(
                    af[ti], bfr[tj], acc[ti][tj], 0, 0, 0);
        __syncthreads();
    }
#pragma unroll
    for (int tj = 0; tj < 4; ++tj) {
        int gn = bn + tj * 16 + m16;
        float bv = bias[gn];
#pragma unroll
        for (int ti = 0; ti < 2; ++ti) {
            int gm0 = bm + wm + ti * 16 + q * 4;
            float t[4];
#pragma unroll
            for (int r = 0; r < 4; ++r) {
                float v = acc[ti][tj][r] + bv;
                v = (v > 15.f) ? v : log1pf(__expf(v));
                t[r] = fminf(fmaxf(v, 0.001f), 0.1f);
            }
            *(float4*)(Cf + (size_t)gn * 2048 + gm0) =
                make_float4(t[0], t[1], t[2], t[3]);
        }
    }
}

// ---------------- scan7: lane=(c,n), DPP reduce, packed bc16, native exp2 ----------
__global__ __launch_bounds__(512) void scan7_k(
    const float* __restrict__ deltaT,
    const u16* __restrict__ uT,
    const u16* __restrict__ bc16,
    const float* __restrict__ A_log,
    const float* __restrict__ Dvec,
    const u16* __restrict__ resT,
    u16* __restrict__ zT)
{
    __shared__ float lP[2][32][16], lS[2][32][16], lI[2][32][16];
    __shared__ float yrow[2048];
    const int h = blockIdx.x;
    const int tid = threadIdx.x;
    const int n = tid & 15;
    const int c = tid >> 4;
    const int l0 = c * 32;

    const float An2 = -__expf(A_log[h * 16 + n]) * 1.442695041f;
    const float* drow = deltaT + (size_t)h * 2048;
    const u16*   urow = uT     + (size_t)h * 2048;

    float s0 = 0.f, s1 = 0.f, T0 = 0.f, T1 = 0.f;
    for (int j = 0; j < 32; ++j) {
        int l = l0 + j;
        float2 dtv = *(const float2*)(drow + 2 * l);
        u32 uv = *(const u32*)(urow + 2 * l);
        float uu0 = __uint_as_float(uv << 16);
        float uu1 = __uint_as_float(uv & 0xffff0000u);
        u32 w0 = *(const u32*)(bc16 + (size_t)(2 * l) * 32 + 2 * n);
        u32 w1 = *(const u32*)(bc16 + (size_t)(2 * l + 1) * 32 + 2 * n);
        float e0 = fexp2(dtv.x * An2);
        float e1 = fexp2(dtv.y * An2);
        s0 = fmaf(e0, s0, dtv.x * uu0 * __uint_as_float(w0 << 16));
        s1 = fmaf(e1, s1, dtv.y * uu1 * __uint_as_float(w1 << 16));
        T0 += dtv.x;
        T1 += dtv.y;
    }
    lP[0][c][n] = fexp2(T0 * An2); lS[0][c][n] = s0;
    lP[1][c][n] = fexp2(T1 * An2); lS[1][c][n] = s1;
    __syncthreads();
    if (tid < 32) {
        int bb = tid >> 4, nn = tid & 15;
        float X = 0.f;
#pragma unroll
        for (int cc = 0; cc < 32; ++cc) {
            lI[bb][cc][nn] = X;
            X = fmaf(lP[bb][cc][nn], X, lS[bb][cc][nn]);
        }
    }
    __syncthreads();

    s0 = lI[0][c][n];
    s1 = lI[1][c][n];
    const float Dh = Dvec[h];
    for (int j = 0; j < 32; ++j) {
        int l = l0 + j;
        float2 dtv = *(const float2*)(drow + 2 * l);
        u32 uv = *(const u32*)(urow + 2 * l);
        float uu0 = __uint_as_float(uv << 16);
        float uu1 = __uint_as_float(uv & 0xffff0000u);
        u32 w0 = *(const u32*)(bc16 + (size_t)(2 * l) * 32 + 2 * n);
        u32 w1 = *(const u32*)(bc16 + (size_t)(2 * l + 1) * 32 + 2 * n);
        float e0 = fexp2(dtv.x * An2);
        float e1 = fexp2(dtv.y * An2);
        s0 = fmaf(e0, s0, dtv.x * uu0 * __uint_as_float(w0 << 16));
        s1 = fmaf(e1, s1, dtv.y * uu1 * __uint_as_float(w1 << 16));
        float v0 = dpp_red16(__uint_as_float(w0 & 0xffff0000u) * s0);
        float v1 = dpp_red16(__uint_as_float(w1 & 0xffff0000u) * s1);
        if (n == 0) {
            yrow[2 * l]     = v0 + uu0 * Dh;
            yrow[2 * l + 1] = v1 + uu1 * Dh;
        }
    }
    __syncthreads();
    {
        int t0 = tid * 4;
        ushort4v rv = *(const ushort4v*)(resT + (size_t)h * 2048 + t0);
        u16 o[4];
#pragma unroll
        for (int i = 0; i < 4; ++i) {
            float r = bf2f(rv[i]);
            float y = yrow[t0 + i];
            o[i] = f2bf(y * (r / (1.f + __expf(-r))));
        }
        *(ulong1*)(zT + (size_t)h * 2048 + t0) = *(ulong1*)o;
    }
}

extern "C" void kernel_launch(void* const* d_in, const int* in_sizes, int n_in,
                              void* d_out, int out_size, void* d_ws, size_t ws_size,
                              hipStream_t stream)
{
    const float* x      = (const float*)d_in[0];
    const float* W_in   = (const float*)d_in[1];
    const float* W_conv = (const float*)d_in[2];
    const float* b_conv = (const float*)d_in[3];
    const float* A_log  = (const float*)d_in[4];
    const float* Dv     = (const float*)d_in[5];
    const float* W_ssm  = (const float*)d_in[6];
    const float* W_dt   = (const float*)d_in[7];
    const float* b_dt   = (const float*)d_in[8];
    const float* W_out  = (const float*)d_in[9];
    float* out = (float*)d_out;

    char* wsc = (char*)d_ws;
    u16*   xb     = (u16*)wsc;                 // ws+0 (..G1)
    float* projb  = (float*)wsc;               // ws+0 (conv2..scan) — ALIASES xb!
    u16*   bc16   = (u16*)(wsc + (3u << 20));
    u16*   WT_in  = (u16*)(wsc + (4u << 20));
    u16*   u_mh   = (u16*)(wsc + (4u << 20));
    u16*   z_mh   = (u16*)(wsc + (4u << 20));
    u16*   xsbf   = (u16*)(wsc + (12u << 20));
    u16*   zT     = xsbf;
    u16*   resT   = (u16*)(wsc + (20u << 20));
    u16*   WT_cv  = (u16*)(wsc + (28u << 20));
    float* deltaT = (float*)(wsc + (28u << 20));
    u16*   uT     = (u16*)(wsc + (44u << 20));
    u16*   WT_out = (u16*)(wsc + (52u << 20));
    u16*   WT_ssm = (u16*)(wsc + (56u << 20));
    u16*   WT_dt  = (u16*)(wsc + (56u << 20) + (512u << 10));

    dim3 blk(256);

    // prep: 5 transposes + x convert + out zeroing (7776 blocks, one launch)
    prep_k<<<dim3(7776), blk, 0, stream>>>(
        W_conv, WT_cv, W_in, WT_in, W_out, WT_out, W_ssm, WT_ssm, W_dt, WT_dt,
        x, xb, out);

    // G1: xs[m][ch] | resT[h][m]  (last reader of xb; 128x128 tiles)
    gls2_k<0><<<dim3(32, 16), blk, 0, stream>>>(
        xb, 1024, WT_in, 1024, nullptr, 0, xsbf, resT, 16);

    // C: tap-strip conv -> u_mh + uT; zeros projb (safe: xb dead after G1)
    conv2_k<<<dim3(32, 16), blk, 0, stream>>>(
        xsbf, WT_cv, b_conv, u_mh, uT, projb);

    // G3: proj (split-K=8 atomics)
    g3_k<<<dim3(2, 16, 8), blk, 0, stream>>>(u_mh, WT_ssm, projb);

    // BC cols -> bc16 (64 blocks)
    cvtp_k<<<dim3(64), blk, 0, stream>>>(projb, bc16);

    // G4: deltaT (dt converted inline from projb)
    g4_k<<<dim3(32, 16), blk, 0, stream>>>(projb, WT_dt, b_dt, deltaT);

    scan7_k<<<dim3(2048), dim3(512), 0, stream>>>(
        deltaT, uT, bc16, A_log, Dv, resT, zT);

    tbf_k<<<dim3(32, 32), blk, 0, stream>>>(zT, z_mh);

    // G5: out = z_mh @ WT_out^T, 128x128 tiles, split-K=4, fp32 atomic accumulate
    gls2_k<3><<<dim3(8, 16, 4), blk, 0, stream>>>(
        z_mh, 2048, WT_out, 2048, out, 1024, nullptr, nullptr, 8);
}

// Round 15
// 312.581 us; speedup vs baseline: 1.0496x; 1.0496x over previous
//
#include <hip/hip_runtime.h>
#include <math.h>

// L=1024 B=2 F=1024 E=2 H=2048 N=16 R=64 K=4, M=2048 rows (m = l*2+b).
// Round-15: unbundle r14. GEMMs reverted to r13-proven gls_k 128x64
// (G1 1024 blocks; G5 split-K=2, 512 blocks — r14's gls2 128x128 halved
// blocks and doubled G5 atomics, net regression). Kept from r14: prep_k
// fused out-zeroing, conv2 zeroes projb, g4 inline dt convert. New: cvtp
// folded into g4's first 64 blocks. 8 dispatches (r13 had 11).

typedef unsigned short u16;
typedef unsigned int u32;
typedef __attribute__((ext_vector_type(8))) short short8;
typedef __attribute__((ext_vector_type(4))) float floatx4;
typedef __attribute__((ext_vector_type(4))) u16 ushort4v;

__device__ __forceinline__ u16 f2bf(float f) {
    u32 u = __float_as_uint(f);
    return (u16)((u + 0x7fffu + ((u >> 16) & 1u)) >> 16);
}
__device__ __forceinline__ float bf2f(u16 v) {
    return __uint_as_float((u32)v << 16);
}
__device__ __forceinline__ float fexp2(float x) {
    return __builtin_amdgcn_exp2f(x);   // bare v_exp_f32
}

// 16-lane sum reduction on the VALU pipe (DPP), no DS ops.
__device__ __forceinline__ float dpp_red16(float v) {
    v += __uint_as_float((u32)__builtin_amdgcn_update_dpp(
        0, (int)__float_as_uint(v), 0xB1, 0xF, 0xF, true));
    v += __uint_as_float((u32)__builtin_amdgcn_update_dpp(
        0, (int)__float_as_uint(v), 0x4E, 0xF, 0xF, true));
    v += __uint_as_float((u32)__builtin_amdgcn_update_dpp(
        0, (int)__float_as_uint(v), 0x141, 0xF, 0xF, true));
    v += __uint_as_float((u32)__builtin_amdgcn_update_dpp(
        0, (int)__float_as_uint(v), 0x128, 0xF, 0xF, true));
    return v;
}

// async global->LDS, 16 bytes per lane
__device__ __forceinline__ void gl_lds16(const u16* g, u16* l) {
    auto gp = reinterpret_cast<const __attribute__((address_space(1))) u32*>(
        reinterpret_cast<uintptr_t>(g));
    auto lp = reinterpret_cast<__attribute__((address_space(3))) u32*>(
        reinterpret_cast<uintptr_t>(l));
    __builtin_amdgcn_global_load_lds(gp, lp, 16, 0, 0);
}

// ---------------- device transpose body (fp32 -> bf16, S[R][C] -> D[C][R]) --------
__device__ __forceinline__ void trans_dev(const float* __restrict__ S,
                                          u16* __restrict__ D, int R, int C,
                                          int bx, int by)
{
    __shared__ u16 t[64][65];
    int br = bx * 64;
    int bc = by * 64;
    int c = threadIdx.x & 63;
    int r0 = threadIdx.x >> 6;
#pragma unroll
    for (int i = 0; i < 16; ++i) {
        int r = r0 + i * 4;
        float v = 0.f;
        if (br + r < R && bc + c < C) v = S[(size_t)(br + r) * C + bc + c];
        t[r][c] = f2bf(v);
    }
    __syncthreads();
    int cc0 = threadIdx.x >> 4;
    int rr0 = (threadIdx.x & 15) * 4;
#pragma unroll
    for (int i = 0; i < 4; ++i) {
        int cc = i * 16 + cc0;
        if (bc + cc < C) {
            ushort4v o;
#pragma unroll
            for (int k = 0; k < 4; ++k) o[k] = t[rr0 + k][cc];
            *(ushort4v*)(D + (size_t)(bc + cc) * R + br + rr0) = o;
        }
    }
}

// ------ prep: all transposes + x convert + out zeroing, one launch (7776 blocks) ---
__global__ __launch_bounds__(256) void prep_k(
    const float* __restrict__ Wc, u16* __restrict__ WTc,
    const float* __restrict__ Wi, u16* __restrict__ WTi,
    const float* __restrict__ Wo, u16* __restrict__ WTo,
    const float* __restrict__ Ws, u16* __restrict__ WTs,
    const float* __restrict__ Wd, u16* __restrict__ WTd,
    const float* __restrict__ x,  u16* __restrict__ xb,
    float* __restrict__ outz)
{
    int b = blockIdx.x;
    if (b < 2048) { trans_dev(Wc, WTc, 4096, 2048, b & 63, b >> 6); return; }
    b -= 2048;
    if (b < 1024) { trans_dev(Wi, WTi, 1024, 4096, b & 15, b >> 4); return; }
    b -= 1024;
    if (b < 512)  { trans_dev(Wo, WTo, 2048, 1024, b & 31, b >> 5); return; }
    b -= 512;
    if (b < 64)   { trans_dev(Ws, WTs, 2048, 96,   b & 31, b >> 5); return; }
    b -= 64;
    if (b < 32)   { trans_dev(Wd, WTd, 64, 2048,   0,      b);      return; }
    b -= 32;
    if (b < 2048) {   // x fp32 -> bf16
        int i = (b * 256 + threadIdx.x) * 4;
        float4 v = *(const float4*)(x + i);
        u16 o[4] = {f2bf(v.x), f2bf(v.y), f2bf(v.z), f2bf(v.w)};
        *(ulong1*)(xb + i) = *(ulong1*)o;
        return;
    }
    b -= 2048;
    {   // zero out (split-K accumulation target)
        int i = (b * 256 + threadIdx.x) * 4;
        *(float4*)(outz + i) = make_float4(0.f, 0.f, 0.f, 0.f);
    }
}

// ---------------- bf16 [2048][2048] transpose (zT -> z_mh) ----------------
__global__ __launch_bounds__(256) void tbf_k(const u16* __restrict__ S,
                                             u16* __restrict__ D)
{
    __shared__ u16 t[64][68];
    int br = blockIdx.x * 64;
    int bc = blockIdx.y * 64;
    int c = threadIdx.x & 63;
    int r0 = threadIdx.x >> 6;
#pragma unroll
    for (int i = 0; i < 16; ++i) {
        int r = r0 + i * 4;
        t[r][c] = S[(size_t)(br + r) * 2048 + bc + c];
    }
    __syncthreads();
#pragma unroll
    for (int i = 0; i < 16; ++i) {
        int r = r0 + i * 4;
        D[(size_t)(bc + r) * 2048 + br + c] = t[c][r];
    }
}

// ================= m97-style GEMM: A[M][K] x B[N][K]^T, tile 128x64, BK=64 =========
// MODE 0: G1 split — bn<2048: xs[m][h] via LDS repack; else resT[h][m] direct
// MODE 3: split-K (gridDim.z), fp32 atomicAdd into zeroed Cf
template<int MODE>
__global__ __launch_bounds__(256) void gls_k(
    const u16* __restrict__ A, int lda,
    const u16* __restrict__ B, int ldb,
    float* __restrict__ Cf, int ldc,
    u16* __restrict__ Cb0, u16* __restrict__ Cb1, int nkt)
{
    __shared__ u16 As[128 * 64];
    __shared__ u16 Bs[64 * 64];
    const int tid = threadIdx.x;
    const int bm = blockIdx.y * 128;
    const int bn = blockIdx.x * 64;
    const int kofs = (MODE == 3) ? blockIdx.z * nkt * 64 : 0;
    const int lane = tid & 63, wave = tid >> 6, wm = wave * 32;
    const int m16 = lane & 15, q = lane >> 4;
    floatx4 acc[2][4] = {};

    const int rsub = lane >> 3;
    const int pch  = lane & 7;

    for (int kt = 0; kt < nkt; ++kt) {
        const int k0 = kofs + kt * 64;
#pragma unroll
        for (int i = 0; i < 4; ++i) {
            int r = i * 32 + wave * 8 + rsub;
            int c = pch ^ (r & 7);
            gl_lds16(A + (size_t)(bm + r) * lda + k0 + c * 8,
                     As + i * 2048 + wave * 512);
        }
#pragma unroll
        for (int i = 0; i < 2; ++i) {
            int r = i * 32 + wave * 8 + rsub;
            int c = pch ^ (r & 7);
            gl_lds16(B + (size_t)(bn + r) * ldb + k0 + c * 8,
                     Bs + i * 2048 + wave * 512);
        }
        __syncthreads();

#pragma unroll
        for (int ks = 0; ks < 2; ++ks) {
            short8 af[2], bfr[4];
#pragma unroll
            for (int ti = 0; ti < 2; ++ti) {
                int r = wm + ti * 16 + m16;
                int p = (ks * 4 + q) ^ (r & 7);
                af[ti] = *(const short8*)(As + r * 64 + p * 8);
            }
#pragma unroll
            for (int tj = 0; tj < 4; ++tj) {
                int r = tj * 16 + m16;
                int p = (ks * 4 + q) ^ (r & 7);
                bfr[tj] = *(const short8*)(Bs + r * 64 + p * 8);
            }
#pragma unroll
            for (int ti = 0; ti < 2; ++ti)
#pragma unroll
                for (int tj = 0; tj < 4; ++tj)
                    acc[ti][tj] = __builtin_amdgcn_mfma_f32_16x16x32_bf16(
                        af[ti], bfr[tj], acc[ti][tj], 0, 0, 0);
        }
        __syncthreads();
    }

    if (MODE == 3) {
#pragma unroll
        for (int tj = 0; tj < 4; ++tj) {
            int gn = bn + tj * 16 + m16;
#pragma unroll
            for (int ti = 0; ti < 2; ++ti) {
                int gm0 = bm + wm + ti * 16 + q * 4;
#pragma unroll
                for (int r = 0; r < 4; ++r)
                    atomicAdd(Cf + (size_t)(gm0 + r) * ldc + gn, acc[ti][tj][r]);
            }
        }
        return;
    }
    if (MODE == 0 && bn >= 2048) {
#pragma unroll
        for (int tj = 0; tj < 4; ++tj) {
            int gn = bn + tj * 16 + m16;
#pragma unroll
            for (int ti = 0; ti < 2; ++ti) {
                int gm0 = bm + wm + ti * 16 + q * 4;
                ushort4v h;
#pragma unroll
                for (int r = 0; r < 4; ++r) h[r] = f2bf(acc[ti][tj][r]);
                *(ushort4v*)(Cb1 + (size_t)(gn - 2048) * 2048 + gm0) = h;
            }
        }
        return;
    }
    // MODE 0 xs-half: repack [m][h] tile via LDS
#pragma unroll
    for (int tj = 0; tj < 4; ++tj) {
#pragma unroll
        for (int ti = 0; ti < 2; ++ti) {
            int lr0 = wm + ti * 16 + q * 4;
#pragma unroll
            for (int r = 0; r < 4; ++r)
                As[(lr0 + r) * 64 + tj * 16 + m16] = f2bf(acc[ti][tj][r]);
        }
    }
    __syncthreads();
    {
        int row = tid >> 1, half = tid & 1;
        u16* gdst = Cb0 + (size_t)(bm + row) * 2048 + bn + half * 32;
        const u16* lsrc = As + row * 64 + half * 32;
#pragma unroll
        for (int i = 0; i < 4; ++i)
            *(short8*)(gdst + i * 8) = *(const short8*)(lsrc + i * 8);
    }
}

// ================= conv2: tap-strip conv GEMM, tile 128x64 ========================
__global__ __launch_bounds__(256) void conv2_k(
    const u16* __restrict__ A,      // xsbf [2048][2048]
    const u16* __restrict__ B,      // WT_cv [2048][4096]
    const float* __restrict__ bias,
    u16* __restrict__ Cb0,          // u_mh [m][h]
    u16* __restrict__ Cb1,          // uT [h][m]
    float* __restrict__ projz)      // projb to zero (for g3)
{
    __shared__ u16 Astrip[136 * 64];
    __shared__ u16 Bs[4 * 64 * 64];
    const int tid = threadIdx.x;
    const int bm = blockIdx.y * 128;
    const int bn = blockIdx.x * 64;
    // zero projb slice (consumed by g3, dispatched later; xb dead after G1)
    {
        int fb = blockIdx.y * gridDim.x + blockIdx.x;   // 0..511
        *(float2*)(projz + fb * 512 + tid * 2) = make_float2(0.f, 0.f);
    }
    const int gofs = (bn >= 1024) ? 1024 : 0;
    const int lane = tid & 63, wave = tid >> 6, wm = wave * 32;
    const int m16 = lane & 15, q = lane >> 4;
    floatx4 acc[2][4] = {};
    const int rsub = lane >> 3;
    const int pch  = lane & 7;

    for (int ch = 0; ch < 16; ++ch) {
        const int ck = ch * 64;
#pragma unroll
        for (int i = 0; i < 4; ++i) {
            int r = i * 32 + wave * 8 + rsub;
            int c = pch ^ (r & 7);
            int rg = bm + r - 6;
            if (rg < 0) rg = 0;
            gl_lds16(A + (size_t)rg * 2048 + gofs + ck + c * 8,
                     Astrip + i * 2048 + wave * 512);
        }
        if (wave == 0) {
            int r = 128 + rsub;
            int c = pch ^ (r & 7);
            int rg = bm + r - 6;
            if (rg > 2047) rg = 2047;
            gl_lds16(A + (size_t)rg * 2048 + gofs + ck + c * 8,
                     Astrip + 4 * 2048);
        }
#pragma unroll
        for (int t = 0; t < 4; ++t)
#pragma unroll
            for (int i = 0; i < 2; ++i) {
                int r = i * 32 + wave * 8 + rsub;
                int c = pch ^ (r & 7);
                gl_lds16(B + (size_t)(bn + r) * 4096 + t * 1024 + ck + c * 8,
                         Bs + t * 4096 + i * 2048 + wave * 512);
            }
        if (bm == 0) {
            asm volatile("s_waitcnt vmcnt(0)" ::: "memory");
            if (tid < 48)
                *(short8*)(Astrip + (tid >> 3) * 64 + (tid & 7) * 8) = short8{};
        }
        __syncthreads();

#pragma unroll
        for (int t = 0; t < 4; ++t) {
#pragma unroll
            for (int ks = 0; ks < 2; ++ks) {
                short8 af[2], bfr[4];
#pragma unroll
                for (int ti = 0; ti < 2; ++ti) {
                    int sr = wm + ti * 16 + m16 + 2 * t;
                    int p = (ks * 4 + q) ^ (sr & 7);
                    af[ti] = *(const short8*)(Astrip + sr * 64 + p * 8);
                }
#pragma unroll
                for (int tj = 0; tj < 4; ++tj) {
                    int br = tj * 16 + m16;
                    int p = (ks * 4 + q) ^ (br & 7);
                    bfr[tj] = *(const short8*)(Bs + t * 4096 + br * 64 + p * 8);
                }
#pragma unroll
                for (int ti = 0; ti < 2; ++ti)
#pragma unroll
                    for (int tj = 0; tj < 4; ++tj)
                        acc[ti][tj] = __builtin_amdgcn_mfma_f32_16x16x32_bf16(
                            af[ti], bfr[tj], acc[ti][tj], 0, 0, 0);
            }
        }
        __syncthreads();
    }

#pragma unroll
    for (int tj = 0; tj < 4; ++tj) {
        int gn = bn + tj * 16 + m16;
        float bv = bias[gn];
#pragma unroll
        for (int ti = 0; ti < 2; ++ti) {
            int lr0 = wm + ti * 16 + q * 4;
            ushort4v h;
#pragma unroll
            for (int r = 0; r < 4; ++r) {
                float v = acc[ti][tj][r] + bv;
                v = v / (1.f + __expf(-v));
                u16 hv = f2bf(v);
                h[r] = hv;
                Astrip[(lr0 + r) * 64 + tj * 16 + m16] = hv;
            }
            *(ushort4v*)(Cb1 + (size_t)gn * 2048 + bm + lr0) = h;
        }
    }
    __syncthreads();
    {
        int row = tid >> 1, half = tid & 1;
        u16* gdst = Cb0 + (size_t)(bm + row) * 2048 + bn + half * 32;
        const u16* lsrc = Astrip + row * 64 + half * 32;
#pragma unroll
        for (int i = 0; i < 4; ++i)
            *(short8*)(gdst + i * 8) = *(const short8*)(lsrc + i * 8);
    }
}

// ---------------- G3: proj = u @ W_ssm, split-K=8 MFMA, interleaved atomics --------
#define APAD 40
__global__ __launch_bounds__(256) void g3_k(
    const u16* __restrict__ A,
    const u16* __restrict__ Bw,
    float* __restrict__ proj)
{
    __shared__ u16 As[128 * APAD];
    __shared__ u16 Bs[64 * APAD];
    const int tid = threadIdx.x;
    const int bn = blockIdx.x * 64;
    const int bm = blockIdx.y * 128;
    const int kb = blockIdx.z * 256;
    const int lane = tid & 63, wave = tid >> 6, wm = wave * 32;
    const int m16 = lane & 15, q = lane >> 4;
    floatx4 acc[2][4] = {};
    const int ar = tid >> 2, ac = (tid & 3) * 8;

    for (int kt = 0; kt < 8; ++kt) {
        const int k0 = kb + kt * 32;
#pragma unroll
        for (int p = 0; p < 2; ++p) {
            int r = ar + p * 64;
            *(short8*)(As + r * APAD + ac) =
                *(const short8*)(A + (size_t)(bm + r) * 2048 + k0 + ac);
        }
        *(short8*)(Bs + ar * APAD + ac) =
            *(const short8*)(Bw + (size_t)(bn + ar) * 2048 + k0 + ac);
        __syncthreads();

        short8 af[2], bfr[4];
#pragma unroll
        for (int ti = 0; ti < 2; ++ti)
            af[ti] = *(const short8*)(As + (wm + ti * 16 + m16) * APAD + q * 8);
#pragma unroll
        for (int tj = 0; tj < 4; ++tj)
            bfr[tj] = *(const short8*)(Bs + (tj * 16 + m16) * APAD + q * 8);
#pragma unroll
        for (int ti = 0; ti < 2; ++ti)
#pragma unroll
            for (int tj = 0; tj < 4; ++tj)
                acc[ti][tj] = __builtin_amdgcn_mfma_f32_16x16x32_bf16(
                    af[ti], bfr[tj], acc[ti][tj], 0, 0, 0);
        __syncthreads();
    }

#pragma unroll
    for (int tj = 0; tj < 4; ++tj) {
        int gn = bn + tj * 16 + m16;
        if (gn >= 96) continue;
        int col = (gn < 16) ? (2 * gn) : (gn < 32 ? 2 * (gn - 16) + 1 : 32 + gn);
#pragma unroll
        for (int ti = 0; ti < 2; ++ti)
#pragma unroll
            for (int r = 0; r < 4; ++r) {
                int gm = bm + wm + ti * 16 + q * 4 + r;
                atomicAdd(proj + (size_t)gm * 128 + col, acc[ti][tj][r]);
            }
    }
}

// ------- G4: deltaT = clip(softplus(dtraw @ W_dt + b_dt))^T, dt inline;
//         first 64 blocks also convert BC cols -> bc16 (fused cvtp) ----------------
__global__ __launch_bounds__(256) void g4_k(
    const float* __restrict__ proj,   // [2048][128], BC at 0..31, dtraw at 64..127
    const u16* __restrict__ B,        // WT_dt bf16 [2048][64]
    const float* __restrict__ bias,
    float* __restrict__ Cf,           // deltaT fp32 [h][m]
    u16* __restrict__ bc)             // bc16 bf16 [2048][32]
{
    __shared__ u16 As[128 * APAD];
    __shared__ u16 Bs[64 * APAD];
    const int tid = threadIdx.x;
    const int bm = blockIdx.y * 128;
    const int bn = blockIdx.x * 64;
    // fused cvtp: first 64 blocks convert proj BC cols -> bc16
    {
        int fb = blockIdx.y * gridDim.x + blockIdx.x;
        if (fb < 64) {
            int g = fb * 256 + tid;
            int m = g >> 3, i = (g & 7) * 4;
            float4 v = *(const float4*)(proj + (size_t)m * 128 + i);
            u16 o[4] = {f2bf(v.x), f2bf(v.y), f2bf(v.z), f2bf(v.w)};
            *(ulong1*)(bc + (size_t)m * 32 + i) = *(ulong1*)o;
        }
    }
    const int lane = tid & 63, wave = tid >> 6, wm = wave * 32;
    const int m16 = lane & 15, q = lane >> 4;
    floatx4 acc[2][4] = {};
    const int ar = tid >> 2, ac = (tid & 3) * 8;

    for (int kt = 0; kt < 2; ++kt) {
        const int k0 = kt * 32;
#pragma unroll
        for (int p = 0; p < 2; ++p) {
            int r = ar + p * 64;
            const float* src = proj + (size_t)(bm + r) * 128 + 64 + k0 + ac;
            float4 v0 = *(const float4*)src;
            float4 v1 = *(const float4*)(src + 4);
            short8 v = {(short)f2bf(v0.x), (short)f2bf(v0.y), (short)f2bf(v0.z),
                        (short)f2bf(v0.w), (short)f2bf(v1.x), (short)f2bf(v1.y),
                        (short)f2bf(v1.z), (short)f2bf(v1.w)};
            *(short8*)(As + r * APAD + ac) = v;
        }
        *(short8*)(Bs + ar * APAD + ac) =
            *(const short8*)(B + (size_t)(bn + ar) * 64 + k0 + ac);
        __syncthreads();
        short8 af[2], bfr[4];
#pragma unroll
        for (int ti = 0; ti < 2; ++ti)
            af[ti] = *(const short8*)(As + (wm + ti * 16 + m16) * APAD + q * 8);
#pragma unroll
        for (int tj = 0; tj < 4; ++tj)
            bfr[tj] = *(const short8*)(Bs + (tj * 16 + m16) * APAD + q * 8);
#pragma unroll
        for (int ti = 0; ti < 2; ++ti)
#pragma unroll
            for (int tj = 0; tj < 4; ++tj)
                acc[ti][tj] = __builtin_amdgcn_mfma_f32_16x16x32_bf16(
                    af[ti], bfr[tj], acc[ti][tj], 0, 0, 0);
        __syncthreads();
    }
#pragma unroll
    for (int tj = 0; tj < 4; ++tj) {
        int gn = bn + tj * 16 + m16;
        float bv = bias[gn];
#pragma unroll
        for (int ti = 0; ti < 2; ++ti) {
            int gm0 = bm + wm + ti * 16 + q * 4;
            float t[4];
#pragma unroll
            for (int r = 0; r < 4; ++r) {
                float v = acc[ti][tj][r] + bv;
                v = (v > 15.f) ? v : log1pf(__expf(v));
                t[r] = fminf(fmaxf(v, 0.001f), 0.1f);
            }
            *(float4*)(Cf + (size_t)gn * 2048 + gm0) =
                make_float4(t[0], t[1], t[2], t[3]);
        }
    }
}

// ---------------- scan7: lane=(c,n), DPP reduce, packed bc16, native exp2 ----------
__global__ __launch_bounds__(512) void scan7_k(
    const float* __restrict__ deltaT,
    const u16* __restrict__ uT,
    const u16* __restrict__ bc16,
    const float* __restrict__ A_log,
    const float* __restrict__ Dvec,
    const u16* __restrict__ resT,
    u16* __restrict__ zT)
{
    __shared__ float lP[2][32][16], lS[2][32][16], lI[2][32][16];
    __shared__ float yrow[2048];
    const int h = blockIdx.x;
    const int tid = threadIdx.x;
    const int n = tid & 15;
    const int c = tid >> 4;
    const int l0 = c * 32;

    const float An2 = -__expf(A_log[h * 16 + n]) * 1.442695041f;
    const float* drow = deltaT + (size_t)h * 2048;
    const u16*   urow = uT     + (size_t)h * 2048;

    float s0 = 0.f, s1 = 0.f, T0 = 0.f, T1 = 0.f;
    for (int j = 0; j < 32; ++j) {
        int l = l0 + j;
        float2 dtv = *(const float2*)(drow + 2 * l);
        u32 uv = *(const u32*)(urow + 2 * l);
        float uu0 = __uint_as_float(uv << 16);
        float uu1 = __uint_as_float(uv & 0xffff0000u);
        u32 w0 = *(const u32*)(bc16 + (size_t)(2 * l) * 32 + 2 * n);
        u32 w1 = *(const u32*)(bc16 + (size_t)(2 * l + 1) * 32 + 2 * n);
        float e0 = fexp2(dtv.x * An2);
        float e1 = fexp2(dtv.y * An2);
        s0 = fmaf(e0, s0, dtv.x * uu0 * __uint_as_float(w0 << 16));
        s1 = fmaf(e1, s1, dtv.y * uu1 * __uint_as_float(w1 << 16));
        T0 += dtv.x;
        T1 += dtv.y;
    }
    lP[0][c][n] = fexp2(T0 * An2); lS[0][c][n] = s0;
    lP[1][c][n] = fexp2(T1 * An2); lS[1][c][n] = s1;
    __syncthreads();
    if (tid < 32) {
        int bb = tid >> 4, nn = tid & 15;
        float X = 0.f;
#pragma unroll
        for (int cc = 0; cc < 32; ++cc) {
            lI[bb][cc][nn] = X;
            X = fmaf(lP[bb][cc][nn], X, lS[bb][cc][nn]);
        }
    }
    __syncthreads();

    s0 = lI[0][c][n];
    s1 = lI[1][c][n];
    const float Dh = Dvec[h];
    for (int j = 0; j < 32; ++j) {
        int l = l0 + j;
        float2 dtv = *(const float2*)(drow + 2 * l);
        u32 uv = *(const u32*)(urow + 2 * l);
        float uu0 = __uint_as_float(uv << 16);
        float uu1 = __uint_as_float(uv & 0xffff0000u);
        u32 w0 = *(const u32*)(bc16 + (size_t)(2 * l) * 32 + 2 * n);
        u32 w1 = *(const u32*)(bc16 + (size_t)(2 * l + 1) * 32 + 2 * n);
        float e0 = fexp2(dtv.x * An2);
        float e1 = fexp2(dtv.y * An2);
        s0 = fmaf(e0, s0, dtv.x * uu0 * __uint_as_float(w0 << 16));
        s1 = fmaf(e1, s1, dtv.y * uu1 * __uint_as_float(w1 << 16));
        float v0 = dpp_red16(__uint_as_float(w0 & 0xffff0000u) * s0);
        float v1 = dpp_red16(__uint_as_float(w1 & 0xffff0000u) * s1);
        if (n == 0) {
            yrow[2 * l]     = v0 + uu0 * Dh;
            yrow[2 * l + 1] = v1 + uu1 * Dh;
        }
    }
    __syncthreads();
    {
        int t0 = tid * 4;
        ushort4v rv = *(const ushort4v*)(resT + (size_t)h * 2048 + t0);
        u16 o[4];
#pragma unroll
        for (int i = 0; i < 4; ++i) {
            float r = bf2f(rv[i]);
            float y = yrow[t0 + i];
            o[i] = f2bf(y * (r / (1.f + __expf(-r))));
        }
        *(ulong1*)(zT + (size_t)h * 2048 + t0) = *(ulong1*)o;
    }
}

extern "C" void kernel_launch(void* const* d_in, const int* in_sizes, int n_in,
                              void* d_out, int out_size, void* d_ws, size_t ws_size,
                              hipStream_t stream)
{
    const float* x      = (const float*)d_in[0];
    const float* W_in   = (const float*)d_in[1];
    const float* W_conv = (const float*)d_in[2];
    const float* b_conv = (const float*)d_in[3];
    const float* A_log  = (const float*)d_in[4];
    const float* Dv     = (const float*)d_in[5];
    const float* W_ssm  = (const float*)d_in[6];
    const float* W_dt   = (const float*)d_in[7];
    const float* b_dt   = (const float*)d_in[8];
    const float* W_out  = (const float*)d_in[9];
    float* out = (float*)d_out;

    char* wsc = (char*)d_ws;
    u16*   xb     = (u16*)wsc;                 // ws+0 (..G1)
    float* projb  = (float*)wsc;               // ws+0 (conv2..scan) — ALIASES xb!
    u16*   bc16   = (u16*)(wsc + (3u << 20));
    u16*   WT_in  = (u16*)(wsc + (4u << 20));
    u16*   u_mh   = (u16*)(wsc + (4u << 20));
    u16*   z_mh   = (u16*)(wsc + (4u << 20));
    u16*   xsbf   = (u16*)(wsc + (12u << 20));
    u16*   zT     = xsbf;
    u16*   resT   = (u16*)(wsc + (20u << 20));
    u16*   WT_cv  = (u16*)(wsc + (28u << 20));
    float* deltaT = (float*)(wsc + (28u << 20));
    u16*   uT     = (u16*)(wsc + (44u << 20));
    u16*   WT_out = (u16*)(wsc + (52u << 20));
    u16*   WT_ssm = (u16*)(wsc + (56u << 20));
    u16*   WT_dt  = (u16*)(wsc + (56u << 20) + (512u << 10));

    dim3 blk(256);

    // prep: 5 transposes + x convert + out zeroing (one launch)
    prep_k<<<dim3(7776), blk, 0, stream>>>(
        W_conv, WT_cv, W_in, WT_in, W_out, WT_out, W_ssm, WT_ssm, W_dt, WT_dt,
        x, xb, out);

    // G1: xs[m][ch] | resT[h][m]  (last reader of xb; r13-proven 128x64 tiles)
    gls_k<0><<<dim3(64, 16), blk, 0, stream>>>(
        xb, 1024, WT_in, 1024, nullptr, 0, xsbf, resT, 16);

    // C: tap-strip conv -> u_mh + uT; zeros projb (safe: xb dead after G1)
    conv2_k<<<dim3(32, 16), blk, 0, stream>>>(
        xsbf, WT_cv, b_conv, u_mh, uT, projb);

    // G3: proj (split-K=8 atomics)
    g3_k<<<dim3(2, 16, 8), blk, 0, stream>>>(u_mh, WT_ssm, projb);

    // G4: deltaT (dt inline) + fused BC->bc16 convert
    g4_k<<<dim3(32, 16), blk, 0, stream>>>(projb, WT_dt, b_dt, deltaT, bc16);

    scan7_k<<<dim3(2048), dim3(512), 0, stream>>>(
        deltaT, uT, bc16, A_log, Dv, resT, zT);

    tbf_k<<<dim3(32, 32), blk, 0, stream>>>(zT, z_mh);

    // G5: out = z_mh @ WT_out^T, r13-proven 128x64, split-K=2, fp32 atomics
    gls_k<3><<<dim3(16, 16, 2), blk, 0, stream>>>(
        z_mh, 2048, WT_out, 2048, out, 1024, nullptr, nullptr, 16);
}